// Round 15
// baseline (442.994 us; speedup 1.0000x reference)
//
#include <hip/hip_runtime.h>
#include <hip/hip_fp16.h>

#define H 150
#define RNUM 35
#define BNUM 5
#define IB 30

typedef unsigned short ushort_t;
typedef unsigned int uint_t;
using bf16x8 = __attribute__((ext_vector_type(8))) short;
using f32x4  = __attribute__((ext_vector_type(4))) float;

__device__ __forceinline__ ushort_t f2bf(float x) {
    union { float f; unsigned u; } v; v.f = x;
    unsigned u = v.u;
    return (ushort_t)((u + 0x7FFF + ((u >> 16) & 1)) >> 16);
}
__device__ __forceinline__ float bfLo(uint_t u) {
    union { unsigned u; float f; } v; v.u = u << 16; return v.f;
}
__device__ __forceinline__ float bfHi(uint_t u) {
    union { unsigned u; float f; } v; v.u = u & 0xffff0000u; return v.f;
}

// =============== preprocessing (R11 structure: monotone rows, compact rec) ===============

__global__ void k_count(const int* __restrict__ ei, const int* __restrict__ et,
                        int E_, int* __restrict__ cnt) {
    for (int e = blockIdx.x * blockDim.x + threadIdx.x; e < E_; e += gridDim.x * blockDim.x) {
        int d = ei[E_ + e];
        int r = et[e];
        atomicAdd(&cnt[d * RNUM + r], 1);
    }
}

#define SPT 2
#define SCAN_BLOCK 256
#define SCAN_SPAN (SPT * SCAN_BLOCK)

__global__ void k_scanA(const int* __restrict__ cnt, int N_,
                        int* __restrict__ blkN, int* __restrict__ blkD) {
    __shared__ int sn[SCAN_BLOCK], sd[SCAN_BLOCK];
    int t = threadIdx.x;
    int base = blockIdx.x * SCAN_SPAN + t * SPT;
    int tn = 0, td = 0;
    for (int k = 0; k < SPT; ++k) {
        int d = base + k;
        if (d < N_) {
            for (int r = 0; r < RNUM; ++r) {
                int c = cnt[d * RNUM + r];
                if (c) { tn++; td += c; }
            }
        }
    }
    sn[t] = tn; sd[t] = td;
    __syncthreads();
    if (t == 0) {
        int an = 0, ad = 0;
        for (int i = 0; i < SCAN_BLOCK; ++i) { an += sn[i]; ad += sd[i]; }
        blkN[blockIdx.x] = an; blkD[blockIdx.x] = ad;
    }
}

__global__ void k_scanB(const int* __restrict__ blkN, const int* __restrict__ blkD,
                        int* __restrict__ blkBN, int* __restrict__ blkBD, int nblk) {
    if (threadIdx.x == 0 && blockIdx.x == 0) {
        int an = 0, ad = 0;
        for (int i = 0; i < nblk; ++i) {
            blkBN[i] = an; blkBD[i] = ad;
            an += blkN[i]; ad += blkD[i];
        }
    }
}

__global__ void k_scanC(const int* __restrict__ cnt, int N_,
                        const int* __restrict__ blkBN, const int* __restrict__ blkBD,
                        int* __restrict__ dstbase, int* __restrict__ segoff,
                        int* __restrict__ segidx, int* __restrict__ relhist2) {
    __shared__ int sn[SCAN_BLOCK], sd[SCAN_BLOCK];
    __shared__ int lhist[RNUM];
    int t = threadIdx.x;
    for (int i = t; i < RNUM; i += SCAN_BLOCK) lhist[i] = 0;
    int base = blockIdx.x * SCAN_SPAN + t * SPT;
    int tn = 0, td = 0;
    for (int k = 0; k < SPT; ++k) {
        int d = base + k;
        if (d < N_) {
            for (int r = 0; r < RNUM; ++r) {
                int c = cnt[d * RNUM + r];
                if (c) { tn++; td += c; }
            }
        }
    }
    sn[t] = tn; sd[t] = td;
    __syncthreads();
    if (t == 0) {
        int an = blkBN[blockIdx.x], ad = blkBD[blockIdx.x];
        for (int i = 0; i < SCAN_BLOCK; ++i) {
            int a = sn[i], b = sd[i];
            sn[i] = an; sd[i] = ad;
            an += a; ad += b;
        }
    }
    __syncthreads();
    int sb = sn[t], eb = sd[t];
    for (int k = 0; k < SPT; ++k) {
        int d = base + k;
        if (d < N_) {
            dstbase[d] = sb;
            for (int r = 0; r < RNUM; ++r) {
                int cell = d * RNUM + r;
                int c = cnt[cell];
                segoff[cell] = eb;
                if (c) { segidx[cell] = sb; sb++; eb += c; atomicAdd(&lhist[r], 1); }
            }
            if (d == N_ - 1) dstbase[N_] = sb;
        }
    }
    __syncthreads();
    for (int i = t; i < RNUM; i += SCAN_BLOCK)
        if (lhist[i]) atomicAdd(&relhist2[i], lhist[i]);
}

__global__ void k_relbase(const int* __restrict__ relhist2, int* __restrict__ relbase2,
                          int* __restrict__ tprefix) {
    if (threadIdx.x == 0 && blockIdx.x == 0) {
        int a = 0, tp = 0;
        for (int r = 0; r < RNUM; ++r) {
            relbase2[r] = a; tprefix[r] = tp;
            a += relhist2[r];
            tp += (relhist2[r] + 15) >> 4;
        }
        relbase2[RNUM] = a; tprefix[RNUM] = tp;
    }
}

__global__ void k_scatter2(const int* __restrict__ ei, const int* __restrict__ et,
                           int E_, int* __restrict__ segoff, int* __restrict__ ssrc2) {
    int e = blockIdx.x * blockDim.x + threadIdx.x;
    if (e >= E_) return;
    int r = et[e];
    int d = ei[E_ + e];
    int pos = atomicAdd(&segoff[d * RNUM + r], 1);
    ssrc2[pos] = ei[e];
}

__global__ void k_relassign(const int* __restrict__ cnt, const int* __restrict__ segoff,
                            const int* __restrict__ segidx, int Ncells,
                            const int* __restrict__ relbase2, int* __restrict__ relfill2,
                            int4* __restrict__ rec) {
    __shared__ int lh[RNUM];
    __shared__ int lbase[RNUM];
    for (int i = threadIdx.x; i < RNUM; i += blockDim.x) lh[i] = 0;
    __syncthreads();
    const int stride = gridDim.x * blockDim.x;
    for (int cell = blockIdx.x * blockDim.x + threadIdx.x; cell < Ncells; cell += stride)
        if (cnt[cell]) atomicAdd(&lh[cell % RNUM], 1);
    __syncthreads();
    for (int i = threadIdx.x; i < RNUM; i += blockDim.x) {
        int c = lh[i];
        lbase[i] = relbase2[i] + (c ? atomicAdd(&relfill2[i], c) : 0);
        lh[i] = 0;
    }
    __syncthreads();
    for (int cell = blockIdx.x * blockDim.x + threadIdx.x; cell < Ncells; cell += stride) {
        int c = cnt[cell];
        if (c) {
            int r = cell % RNUM;
            int pos = lbase[r] + atomicAdd(&lh[r], 1);
            rec[pos] = make_int4(segidx[cell], segoff[cell] - c, c, 0);
        }
    }
}

// merged: W -> MFMA-B-frag bf16 (K pad 30->32) | root -> bf16 160x160 | x -> bf16 rows
__global__ void k_prep(const float* __restrict__ w1, const float* __restrict__ w2,
                       ushort_t* __restrict__ wb1, ushort_t* __restrict__ wb2,
                       const float* __restrict__ r1, const float* __restrict__ r2,
                       ushort_t* __restrict__ B1, ushort_t* __restrict__ B2,
                       const float* __restrict__ x, ushort_t* __restrict__ xbf, int N_) {
    const int tot = RNUM * BNUM * 2 * 16 * 32;        // 179200
    const int t2 = 2 * tot;                            // 358400
    const int t3 = t2 + 2 * 160 * 160;                 // 409600
    const long long t4 = (long long)t3 + (long long)N_ * 160;
    long long i = (long long)blockIdx.x * blockDim.x + threadIdx.x;
    if (i < t2) {
        int idx = (int)i;
        const float* w = (idx < tot) ? w1 : w2;
        ushort_t* wb = (idx < tot) ? wb1 : wb2;
        int q = (idx < tot) ? idx : idx - tot;
        int kj = q & 7;
        int kg = (q >> 3) & 3;
        int cl = (q >> 5) & 15;
        int nh = (q >> 9) & 1;
        int rb = q >> 10;
        int k = kg * 8 + kj;
        int col = nh * 16 + cl;
        ushort_t v = 0;
        if (k < IB && col < IB) v = f2bf(w[(rb * IB + k) * IB + col]);
        wb[q] = v;
    } else if (i < t3) {
        int k = (int)(i - t2);
        const float* src = (k < 160 * 160) ? r1 : r2;
        ushort_t* dst = (k < 160 * 160) ? B1 : B2;
        if (k >= 160 * 160) k -= 160 * 160;
        int row = k / 160, col = k - row * 160;
        dst[k] = (row < H && col < H) ? f2bf(src[row * H + col]) : 0;
    } else if (i < t4) {
        long long k = i - t3;
        int n = (int)(k / 160), c = (int)(k - (long long)n * 160);
        xbf[k] = (c < H) ? f2bf(x[(size_t)n * H + c]) : 0;
    }
}

__global__ __launch_bounds__(256) void k_rootmm(const ushort_t* __restrict__ Abf,
                                                const ushort_t* __restrict__ Bbf,
                                                const float* __restrict__ bias,
                                                float* __restrict__ Cout, int N_) {
    int nt = blockIdx.y;
    int wv = threadIdx.x >> 6, l = threadIdx.x & 63;
    int lr = l & 15, lk = l >> 4;
    bf16x8 bfr[5];
    #pragma unroll
    for (int ks = 0; ks < 5; ++ks) {
        #pragma unroll
        for (int j = 0; j < 8; ++j)
            bfr[ks][j] = (short)Bbf[(ks * 32 + lk * 8 + j) * 160 + nt * 16 + lr];
    }
    int mtiles = N_ / 16;
    int col = nt * 16 + lr;
    float bv = (col < H) ? bias[col] : 0.f;
    for (int mt = blockIdx.x * 4 + wv; mt < mtiles; mt += gridDim.x * 4) {
        f32x4 acc = {0.f, 0.f, 0.f, 0.f};
        const ushort_t* arow = Abf + (size_t)(mt * 16 + lr) * 160 + lk * 8;
        #pragma unroll
        for (int ks = 0; ks < 5; ++ks) {
            bf16x8 af = *reinterpret_cast<const bf16x8*>(arow + ks * 32);
            acc = __builtin_amdgcn_mfma_f32_16x16x32_bf16(af, bfr[ks], acc, 0, 0, 0);
        }
        if (col < H) {
            #pragma unroll
            for (int reg = 0; reg < 4; ++reg)
                Cout[(size_t)(mt * 16 + lk * 4 + reg) * H + col] = acc[reg] + bv;
        }
    }
}

// =============== per-segment transform via MFMA (R11 frozen: static striping,
// compact rec, c==1 fast path) ===============

#define ASTRIDE 168

__global__ __launch_bounds__(256, 4)
void k_seg(const int4* __restrict__ rec, const int* __restrict__ relbase2,
           const int* __restrict__ tprefix,
           const int* __restrict__ ssrc2, const ushort_t* __restrict__ wbf,
           const ushort_t* __restrict__ xbf, __half* __restrict__ tseg,
           const int* __restrict__ rowLoP, const int* __restrict__ rowHiP) {
    __shared__ ushort_t Abuf[4][16 * ASTRIDE];
    __shared__ int relb[RNUM + 1], tpre[RNUM + 1];
    int t = threadIdx.x, wv = t >> 6, l = t & 63;
    int lr = l & 15, kg = l >> 4;
    if (t < RNUM + 1) { relb[t] = relbase2[t]; tpre[t] = tprefix[t]; }

    // zero wave's A region ONCE (NaN-safety: K-pad slots must never hold Inf/NaN
    // bit patterns; B pad rows are zero but Inf*0=NaN inside MFMA)
    {
        uint_t* az = reinterpret_cast<uint_t*>(&Abuf[wv][0]);
        for (int i = l; i < 16 * ASTRIDE / 2; i += 64) az[i] = 0;
    }
    __syncthreads();
    int rowLo = rowLoP[0], rowHi = rowHiP[0];
    int ntile_tot = tpre[RNUM];

    // packed-pair LDS offsets (uint units) for A staging
    int i0 = 2 * l;
    int uA = ((i0 / 30) * 32 + (i0 % 30)) >> 1;
    int i1 = 128 + 2 * l;
    int uB = ((i1 / 30) * 32 + (i1 % 30)) >> 1;   // valid for l < 11

    for (int ti = blockIdx.x * 4 + wv; ti < ntile_tot; ti += gridDim.x * 4) {
        // binary search relation (wave-uniform)
        int r_lo = 0, r_hi = RNUM;
        while (r_hi - r_lo > 1) {
            int m = (r_lo + r_hi) >> 1;
            if (tpre[m] <= ti) r_lo = m; else r_hi = m;
        }
        int r = r_lo;
        int base = relb[r];
        int nseg = relb[r + 1] - base;
        int sbeg = (ti - tpre[r]) << 4;

        // W fragments for this relation (L2-hot)
        bf16x8 bfr[BNUM][2];
        #pragma unroll
        for (int b = 0; b < BNUM; ++b)
            #pragma unroll
            for (int nh = 0; nh < 2; ++nh)
                bfr[b][nh] = *reinterpret_cast<const bf16x8*>(
                    wbf + ((size_t)((r * BNUM + b) * 2 + nh) * 512) + lr * 32 + kg * 8);

        int4 myrec = make_int4(0x7fffffff, 0, 1, 0);
        if (l < 16 && sbeg + l < nseg) myrec = rec[base + sbeg + l];

        // ---- bf16 gather + mean + packed LDS A-stage (c==1 fast path) ----
        uint_t* Au = reinterpret_cast<uint_t*>(&Abuf[wv][0]);
        for (int s = 0; s < 16; ++s) {
            int row = __builtin_amdgcn_readfirstlane(__shfl(myrec.x, s));
            if (row < rowLo || row >= rowHi) continue;
            int eo = __builtin_amdgcn_readfirstlane(__shfl(myrec.y, s));
            int c  = __builtin_amdgcn_readfirstlane(__shfl(myrec.z, s));
            int src0 = ssrc2[eo];                       // uniform addr -> scalar broadcast
            const uint_t* rowU = reinterpret_cast<const uint_t*>(xbf + (size_t)src0 * 160);
            uint_t u0 = rowU[l];
            uint_t u1 = 0;
            if (l < 11) u1 = rowU[64 + l];
            if (c == 1) {
                // mean of one bf16 row == the row: direct copy, zero VALU math
                Au[s * 84 + uA] = u0;
                if (l < 11) Au[s * 84 + uB] = u1;
            } else {
                float a0 = bfLo(u0), a1 = bfHi(u0);
                float a2 = bfLo(u1), a3 = bfHi(u1);
                for (int k = 1; k < c; ++k) {
                    int src = ssrc2[eo + k];
                    const uint_t* rU = reinterpret_cast<const uint_t*>(
                        xbf + (size_t)src * 160);
                    uint_t v0 = rU[l];
                    a0 += bfLo(v0); a1 += bfHi(v0);
                    if (l < 11) {
                        uint_t v1 = rU[64 + l];
                        a2 += bfLo(v1); a3 += bfHi(v1);
                    }
                }
                float inv = 1.0f / (float)c;
                Au[s * 84 + uA] = (uint_t)f2bf(a0 * inv) | ((uint_t)f2bf(a1 * inv) << 16);
                if (l < 11)
                    Au[s * 84 + uB] = (uint_t)f2bf(a2 * inv) | ((uint_t)f2bf(a3 * inv) << 16);
            }
        }

        int rg[4]; bool rok[4];
        #pragma unroll
        for (int q = 0; q < 4; ++q) {
            rg[q] = __shfl(myrec.x, kg * 4 + q);
            rok[q] = (rg[q] >= rowLo) && (rg[q] < rowHi);
        }

        // ---- MFMA transform + fp16 store (invalid rows store-masked) ----
        #pragma unroll
        for (int b = 0; b < BNUM; ++b) {
            bf16x8 af = *reinterpret_cast<const bf16x8*>(
                &Abuf[wv][lr * ASTRIDE + b * 32 + kg * 8]);
            f32x4 z = {0.f, 0.f, 0.f, 0.f};
            f32x4 acc0 = __builtin_amdgcn_mfma_f32_16x16x32_bf16(af, bfr[b][0], z, 0, 0, 0);
            f32x4 acc1 = __builtin_amdgcn_mfma_f32_16x16x32_bf16(af, bfr[b][1], z, 0, 0, 0);
            #pragma unroll
            for (int q = 0; q < 4; ++q) {
                if (rok[q]) {
                    __half* orow = tseg + (size_t)(rg[q] - rowLo) * H + b * IB;
                    orow[lr] = __float2half(acc0[q]);
                    if (lr < 14) orow[16 + lr] = __float2half(acc1[q]);
                }
            }
        }
    }
}

// =============== per-dst aggregation (dst-major contiguous tseg) ===============

__global__ __launch_bounds__(256)
void k_aggadd(const __half* __restrict__ tseg, const int* __restrict__ dstbase,
              const float* __restrict__ rootsrc, float* __restrict__ fout,
              ushort_t* __restrict__ Abf, int relu, int s0, int s1) {
    int t = threadIdx.x, wv = t >> 6, l = t & 63;
    int segBase = dstbase[s0];
    for (int d = s0 + blockIdx.x * 4 + wv; d < s1; d += gridDim.x * 4) {
        int a = dstbase[d], bnd = dstbase[d + 1];
        const float* brow = rootsrc + (size_t)d * H;
        float2 acc0 = *reinterpret_cast<const float2*>(brow + 2 * l);
        float2 acc1 = make_float2(0.f, 0.f);
        if (l < 11) acc1 = *reinterpret_cast<const float2*>(brow + 128 + 2 * l);
        for (int s = a; s < bnd; ++s) {
            const __half2* trow = reinterpret_cast<const __half2*>(
                tseg + (size_t)(s - segBase) * H);
            float2 v = __half22float2(trow[l]);
            acc0.x += v.x; acc0.y += v.y;
            if (l < 11) {
                float2 v1 = __half22float2(trow[64 + l]);
                acc1.x += v1.x; acc1.y += v1.y;
            }
        }
        if (relu) {
            acc0.x = fmaxf(acc0.x, 0.f); acc0.y = fmaxf(acc0.y, 0.f);
            acc1.x = fmaxf(acc1.x, 0.f); acc1.y = fmaxf(acc1.y, 0.f);
        }
        if (fout) {
            float* frow = fout + (size_t)d * H;
            *reinterpret_cast<float2*>(frow + 2 * l) = acc0;
            if (l < 11) *reinterpret_cast<float2*>(frow + 128 + 2 * l) = acc1;
        }
        if (Abf) {
            ushort_t* arow = Abf + (size_t)d * 160;
            uint_t p0 = (uint_t)f2bf(acc0.x) | ((uint_t)f2bf(acc0.y) << 16);
            *reinterpret_cast<uint_t*>(arow + 2 * l) = p0;
            if (l < 11) {
                uint_t p1 = (uint_t)f2bf(acc1.x) | ((uint_t)f2bf(acc1.y) << 16);
                *reinterpret_cast<uint_t*>(arow + 128 + 2 * l) = p1;
            }
            if (l < 5) *reinterpret_cast<uint_t*>(arow + 150 + 2 * l) = 0;
        }
    }
}

extern "C" void kernel_launch(void* const* d_in, const int* in_sizes, int n_in,
                              void* d_out, int out_size, void* d_ws, size_t ws_size,
                              hipStream_t stream) {
    const float* node_emb = (const float*)d_in[0];
    const float* w1 = (const float*)d_in[1];
    const float* root1 = (const float*)d_in[2];
    const float* b1 = (const float*)d_in[3];
    const float* w2 = (const float*)d_in[4];
    const float* root2 = (const float*)d_in[5];
    const float* b2 = (const float*)d_in[6];
    const int* edge_index = (const int*)d_in[7];
    const int* edge_type = (const int*)d_in[8];
    int N_ = in_sizes[0] / H;
    int E_ = in_sizes[8];
    float* out = (float*)d_out;

    const int Ncells = N_ * RNUM;
    const int wbtot = RNUM * BNUM * 2 * 16 * 32;

    int* ws = (int*)d_ws;
    size_t off = 0;
    int* cnt      = ws + off; off += Ncells;
    int* relhist2 = ws + off; off += 64;
    int* relfill2 = ws + off; off += 64;
    size_t zero_units = off;
    int* relbase2 = ws + off; off += 64;
    int* tprefix  = ws + off; off += 64;
    int* blkN     = ws + off; off += 64;
    int* blkD     = ws + off; off += 64;
    int* blkBN    = ws + off; off += 64;
    int* blkBD    = ws + off; off += 64;
    int* dstbase  = ws + off; off += N_ + 2;
    int* segoff   = ws + off; off += Ncells;
    int* segidx   = ws + off; off += Ncells;
    int* ssrc2    = ws + off; off += E_;
    off = (off + 3) & ~(size_t)3;
    int4* rec     = (int4*)(ws + off); off += (size_t)4 * Ncells;
    ushort_t* wbf1 = (ushort_t*)(ws + off); off += wbtot / 2;
    ushort_t* wbf2 = (ushort_t*)(ws + off); off += wbtot / 2;
    ushort_t* Bbf1 = (ushort_t*)(ws + off); off += 12800;
    ushort_t* Bbf2 = (ushort_t*)(ws + off); off += 12800;
    ushort_t* xbf  = (ushort_t*)(ws + off); off += (size_t)N_ * 160 / 2;
    ushort_t* Abf  = (ushort_t*)(ws + off); off += (size_t)N_ * 160 / 2;
    float* rootbuf = (float*)(ws + off); off += (size_t)N_ * H;
    __half* tseg  = (__half*)(ws + off);
    size_t tsegOffB = off * 4;

    size_t availB = (ws_size > tsegOffB) ? (ws_size - tsegOffB) : 0;
    long long dps_ll = (long long)(availB / ((size_t)RNUM * H * 2));
    int dps = (dps_ll > N_) ? N_ : (int)dps_ll;
    if (dps < 1) dps = 1;
    int nstripe = (N_ + dps - 1) / dps;

    hipMemsetAsync(cnt, 0, zero_units * 4, stream);

    k_count<<<512, 256, 0, stream>>>(edge_index, edge_type, E_, cnt);
    int nscan = (N_ + SCAN_SPAN - 1) / SCAN_SPAN;
    k_scanA<<<nscan, SCAN_BLOCK, 0, stream>>>(cnt, N_, blkN, blkD);
    k_scanB<<<1, 64, 0, stream>>>(blkN, blkD, blkBN, blkBD, nscan);
    k_scanC<<<nscan, SCAN_BLOCK, 0, stream>>>(cnt, N_, blkBN, blkBD, dstbase, segoff,
                                              segidx, relhist2);
    k_relbase<<<1, 64, 0, stream>>>(relhist2, relbase2, tprefix);
    k_scatter2<<<(E_ + 255) / 256, 256, 0, stream>>>(edge_index, edge_type, E_, segoff, ssrc2);
    k_relassign<<<64, 256, 0, stream>>>(cnt, segoff, segidx, Ncells, relbase2, relfill2, rec);
    long long preptot = 2LL * wbtot + 2 * 160 * 160 + (long long)N_ * 160;
    k_prep<<<(int)((preptot + 255) / 256), 256, 0, stream>>>(
        w1, w2, wbf1, wbf2, root1, root2, Bbf1, Bbf2, node_emb, xbf, N_);

    const int SEG_GRID = 1792;

    // ---- layer 1: gather from xbf (bf16) ----
    k_rootmm<<<dim3(40, 10), 256, 0, stream>>>(xbf, Bbf1, b1, rootbuf, N_);
    for (int st = 0; st < nstripe; ++st) {
        int s0 = st * dps;
        int s1 = s0 + dps; if (s1 > N_) s1 = N_;
        k_seg<<<SEG_GRID, 256, 0, stream>>>(rec, relbase2, tprefix, ssrc2, wbf1, xbf, tseg,
                                            dstbase + s0, dstbase + s1);
        k_aggadd<<<1280, 256, 0, stream>>>(tseg, dstbase, rootbuf, (float*)nullptr, Abf,
                                           1, s0, s1);
    }

    // ---- layer 2: gather from Abf (bf16) ----
    k_rootmm<<<dim3(40, 10), 256, 0, stream>>>(Abf, Bbf2, b2, out, N_);
    for (int st = 0; st < nstripe; ++st) {
        int s0 = st * dps;
        int s1 = s0 + dps; if (s1 > N_) s1 = N_;
        k_seg<<<SEG_GRID, 256, 0, stream>>>(rec, relbase2, tprefix, ssrc2, wbf2, Abf, tseg,
                                            dstbase + s0, dstbase + s1);
        k_aggadd<<<1280, 256, 0, stream>>>(tseg, dstbase, out, out, (ushort_t*)nullptr,
                                           0, s0, s1);
    }
}

// Round 16
// 420.914 us; speedup vs baseline: 1.0525x; 1.0525x over previous
//
#include <hip/hip_runtime.h>
#include <hip/hip_fp16.h>

#define H 150
#define RNUM 35
#define BNUM 5
#define IB 30

typedef unsigned short ushort_t;
typedef unsigned int uint_t;
using bf16x8 = __attribute__((ext_vector_type(8))) short;
using f32x4  = __attribute__((ext_vector_type(4))) float;

__device__ __forceinline__ ushort_t f2bf(float x) {
    union { float f; unsigned u; } v; v.f = x;
    unsigned u = v.u;
    return (ushort_t)((u + 0x7FFF + ((u >> 16) & 1)) >> 16);
}
__device__ __forceinline__ float bfLo(uint_t u) {
    union { unsigned u; float f; } v; v.u = u << 16; return v.f;
}
__device__ __forceinline__ float bfHi(uint_t u) {
    union { unsigned u; float f; } v; v.u = u & 0xffff0000u; return v.f;
}

// =============== preprocessing (monotone rows, compact rec, fused relassign) ===============

__global__ void k_count(const int* __restrict__ ei, const int* __restrict__ et,
                        int E_, int* __restrict__ cnt) {
    for (int e = blockIdx.x * blockDim.x + threadIdx.x; e < E_; e += gridDim.x * blockDim.x) {
        int d = ei[E_ + e];
        int r = et[e];
        atomicAdd(&cnt[d * RNUM + r], 1);
    }
}

#define SPT 2
#define SCAN_BLOCK 256
#define SCAN_SPAN (SPT * SCAN_BLOCK)

// pass A: per-block totals (segments, edges) + per-block per-rel active histogram
__global__ void k_scanA(const int* __restrict__ cnt, int N_,
                        int* __restrict__ blkN, int* __restrict__ blkD,
                        int* __restrict__ blkRelH) {
    __shared__ int sn[SCAN_BLOCK], sd[SCAN_BLOCK];
    __shared__ int lhist[RNUM];
    int t = threadIdx.x;
    for (int i = t; i < RNUM; i += SCAN_BLOCK) lhist[i] = 0;
    __syncthreads();
    int base = blockIdx.x * SCAN_SPAN + t * SPT;
    int tn = 0, td = 0;
    for (int k = 0; k < SPT; ++k) {
        int d = base + k;
        if (d < N_) {
            for (int r = 0; r < RNUM; ++r) {
                int c = cnt[d * RNUM + r];
                if (c) { tn++; td += c; atomicAdd(&lhist[r], 1); }
            }
        }
    }
    sn[t] = tn; sd[t] = td;
    __syncthreads();
    if (t == 0) {
        int an = 0, ad = 0;
        for (int i = 0; i < SCAN_BLOCK; ++i) { an += sn[i]; ad += sd[i]; }
        blkN[blockIdx.x] = an; blkD[blockIdx.x] = ad;
    }
    for (int i = t; i < RNUM; i += SCAN_BLOCK)
        blkRelH[blockIdx.x * RNUM + i] = lhist[i];
}

// pass B (tiny): block prefixes + per-rel absolute rec bases + relbase2/tprefix
__global__ void k_scanB(const int* __restrict__ blkN, const int* __restrict__ blkD,
                        const int* __restrict__ blkRelH, int nblk,
                        int* __restrict__ blkBN, int* __restrict__ blkBD,
                        int* __restrict__ blkRelBase, int* __restrict__ relbase2,
                        int* __restrict__ tprefix) {
    __shared__ int relTot[RNUM];
    __shared__ int relB[RNUM];
    int t = threadIdx.x;
    if (t == 0) {
        int an = 0, ad = 0;
        for (int i = 0; i < nblk; ++i) {
            blkBN[i] = an; blkBD[i] = ad;
            an += blkN[i]; ad += blkD[i];
        }
    }
    if (t < RNUM) {
        int s = 0;
        for (int b = 0; b < nblk; ++b) s += blkRelH[b * RNUM + t];
        relTot[t] = s;
    }
    __syncthreads();
    if (t == 0) {
        int a = 0, tp = 0;
        for (int r = 0; r < RNUM; ++r) {
            relbase2[r] = a; relB[r] = a; tprefix[r] = tp;
            a += relTot[r];
            tp += (relTot[r] + 15) >> 4;
        }
        relbase2[RNUM] = a; tprefix[RNUM] = tp;
    }
    __syncthreads();
    if (t < RNUM) {
        int run = relB[t];
        for (int b = 0; b < nblk; ++b) {
            blkRelBase[b * RNUM + t] = run;
            run += blkRelH[b * RNUM + t];
        }
    }
}

// pass C: dstbase/segoff + rec written inline (fused relassign; row ids globally
// dst-monotone; within-rel rec order block-scrambled — proven harmless in R11)
__global__ void k_scanC(const int* __restrict__ cnt, int N_,
                        const int* __restrict__ blkBN, const int* __restrict__ blkBD,
                        const int* __restrict__ blkRelBase,
                        int* __restrict__ dstbase, int* __restrict__ segoff,
                        int4* __restrict__ rec) {
    __shared__ int sn[SCAN_BLOCK], sd[SCAN_BLOCK];
    __shared__ int lrank[RNUM], lbase[RNUM];
    int t = threadIdx.x;
    for (int i = t; i < RNUM; i += SCAN_BLOCK) {
        lrank[i] = 0;
        lbase[i] = blkRelBase[blockIdx.x * RNUM + i];
    }
    int base = blockIdx.x * SCAN_SPAN + t * SPT;
    int tn = 0, td = 0;
    for (int k = 0; k < SPT; ++k) {
        int d = base + k;
        if (d < N_) {
            for (int r = 0; r < RNUM; ++r) {
                int c = cnt[d * RNUM + r];
                if (c) { tn++; td += c; }
            }
        }
    }
    sn[t] = tn; sd[t] = td;
    __syncthreads();
    if (t == 0) {
        int an = blkBN[blockIdx.x], ad = blkBD[blockIdx.x];
        for (int i = 0; i < SCAN_BLOCK; ++i) {
            int a = sn[i], b = sd[i];
            sn[i] = an; sd[i] = ad;
            an += a; ad += b;
        }
    }
    __syncthreads();
    int sb = sn[t], eb = sd[t];
    for (int k = 0; k < SPT; ++k) {
        int d = base + k;
        if (d < N_) {
            dstbase[d] = sb;
            for (int r = 0; r < RNUM; ++r) {
                int cell = d * RNUM + r;
                int c = cnt[cell];
                segoff[cell] = eb;
                if (c) {
                    int pos = lbase[r] + atomicAdd(&lrank[r], 1);
                    rec[pos] = make_int4(sb, eb, c, 0);
                    sb++; eb += c;
                }
            }
            if (d == N_ - 1) dstbase[N_] = sb;
        }
    }
}

__global__ void k_scatter2(const int* __restrict__ ei, const int* __restrict__ et,
                           int E_, int* __restrict__ segoff, int* __restrict__ ssrc2) {
    int e = blockIdx.x * blockDim.x + threadIdx.x;
    if (e >= E_) return;
    int r = et[e];
    int d = ei[E_ + e];
    int pos = atomicAdd(&segoff[d * RNUM + r], 1);
    ssrc2[pos] = ei[e];
}

// merged: W -> MFMA-B-frag bf16 (K pad 30->32) | root -> bf16 160x160 | x -> bf16 rows
__global__ void k_prep(const float* __restrict__ w1, const float* __restrict__ w2,
                       ushort_t* __restrict__ wb1, ushort_t* __restrict__ wb2,
                       const float* __restrict__ r1, const float* __restrict__ r2,
                       ushort_t* __restrict__ B1, ushort_t* __restrict__ B2,
                       const float* __restrict__ x, ushort_t* __restrict__ xbf, int N_) {
    const int tot = RNUM * BNUM * 2 * 16 * 32;        // 179200
    const int t2 = 2 * tot;                            // 358400
    const int t3 = t2 + 2 * 160 * 160;                 // 409600
    const long long t4 = (long long)t3 + (long long)N_ * 160;
    long long i = (long long)blockIdx.x * blockDim.x + threadIdx.x;
    if (i < t2) {
        int idx = (int)i;
        const float* w = (idx < tot) ? w1 : w2;
        ushort_t* wb = (idx < tot) ? wb1 : wb2;
        int q = (idx < tot) ? idx : idx - tot;
        int kj = q & 7;
        int kg = (q >> 3) & 3;
        int cl = (q >> 5) & 15;
        int nh = (q >> 9) & 1;
        int rb = q >> 10;
        int k = kg * 8 + kj;
        int col = nh * 16 + cl;
        ushort_t v = 0;
        if (k < IB && col < IB) v = f2bf(w[(rb * IB + k) * IB + col]);
        wb[q] = v;
    } else if (i < t3) {
        int k = (int)(i - t2);
        const float* src = (k < 160 * 160) ? r1 : r2;
        ushort_t* dst = (k < 160 * 160) ? B1 : B2;
        if (k >= 160 * 160) k -= 160 * 160;
        int row = k / 160, col = k - row * 160;
        dst[k] = (row < H && col < H) ? f2bf(src[row * H + col]) : 0;
    } else if (i < t4) {
        long long k = i - t3;
        int n = (int)(k / 160), c = (int)(k - (long long)n * 160);
        xbf[k] = (c < H) ? f2bf(x[(size_t)n * H + c]) : 0;
    }
}

__global__ __launch_bounds__(256) void k_rootmm(const ushort_t* __restrict__ Abf,
                                                const ushort_t* __restrict__ Bbf,
                                                const float* __restrict__ bias,
                                                float* __restrict__ Cout, int N_) {
    int nt = blockIdx.y;
    int wv = threadIdx.x >> 6, l = threadIdx.x & 63;
    int lr = l & 15, lk = l >> 4;
    bf16x8 bfr[5];
    #pragma unroll
    for (int ks = 0; ks < 5; ++ks) {
        #pragma unroll
        for (int j = 0; j < 8; ++j)
            bfr[ks][j] = (short)Bbf[(ks * 32 + lk * 8 + j) * 160 + nt * 16 + lr];
    }
    int mtiles = N_ / 16;
    int col = nt * 16 + lr;
    float bv = (col < H) ? bias[col] : 0.f;
    for (int mt = blockIdx.x * 4 + wv; mt < mtiles; mt += gridDim.x * 4) {
        f32x4 acc = {0.f, 0.f, 0.f, 0.f};
        const ushort_t* arow = Abf + (size_t)(mt * 16 + lr) * 160 + lk * 8;
        #pragma unroll
        for (int ks = 0; ks < 5; ++ks) {
            bf16x8 af = *reinterpret_cast<const bf16x8*>(arow + ks * 32);
            acc = __builtin_amdgcn_mfma_f32_16x16x32_bf16(af, bfr[ks], acc, 0, 0, 0);
        }
        if (col < H) {
            #pragma unroll
            for (int reg = 0; reg < 4; ++reg)
                Cout[(size_t)(mt * 16 + lk * 4 + reg) * H + col] = acc[reg] + bv;
        }
    }
}

// =============== per-segment transform via MFMA (R11 frozen: static striping,
// compact rec, c==1 fast path) ===============

#define ASTRIDE 168

__global__ __launch_bounds__(256, 4)
void k_seg(const int4* __restrict__ rec, const int* __restrict__ relbase2,
           const int* __restrict__ tprefix,
           const int* __restrict__ ssrc2, const ushort_t* __restrict__ wbf,
           const ushort_t* __restrict__ xbf, __half* __restrict__ tseg,
           const int* __restrict__ rowLoP, const int* __restrict__ rowHiP) {
    __shared__ ushort_t Abuf[4][16 * ASTRIDE];
    __shared__ int relb[RNUM + 1], tpre[RNUM + 1];
    int t = threadIdx.x, wv = t >> 6, l = t & 63;
    int lr = l & 15, kg = l >> 4;
    if (t < RNUM + 1) { relb[t] = relbase2[t]; tpre[t] = tprefix[t]; }

    // zero wave's A region ONCE (NaN-safety: K-pad slots must never hold Inf/NaN
    // bit patterns; B pad rows are zero but Inf*0=NaN inside MFMA)
    {
        uint_t* az = reinterpret_cast<uint_t*>(&Abuf[wv][0]);
        for (int i = l; i < 16 * ASTRIDE / 2; i += 64) az[i] = 0;
    }
    __syncthreads();
    int rowLo = rowLoP[0], rowHi = rowHiP[0];
    int ntile_tot = tpre[RNUM];

    // packed-pair LDS offsets (uint units) for A staging
    int i0 = 2 * l;
    int uA = ((i0 / 30) * 32 + (i0 % 30)) >> 1;
    int i1 = 128 + 2 * l;
    int uB = ((i1 / 30) * 32 + (i1 % 30)) >> 1;   // valid for l < 11

    for (int ti = blockIdx.x * 4 + wv; ti < ntile_tot; ti += gridDim.x * 4) {
        // binary search relation (wave-uniform)
        int r_lo = 0, r_hi = RNUM;
        while (r_hi - r_lo > 1) {
            int m = (r_lo + r_hi) >> 1;
            if (tpre[m] <= ti) r_lo = m; else r_hi = m;
        }
        int r = r_lo;
        int base = relb[r];
        int nseg = relb[r + 1] - base;
        int sbeg = (ti - tpre[r]) << 4;

        // W fragments for this relation (L2-hot)
        bf16x8 bfr[BNUM][2];
        #pragma unroll
        for (int b = 0; b < BNUM; ++b)
            #pragma unroll
            for (int nh = 0; nh < 2; ++nh)
                bfr[b][nh] = *reinterpret_cast<const bf16x8*>(
                    wbf + ((size_t)((r * BNUM + b) * 2 + nh) * 512) + lr * 32 + kg * 8);

        int4 myrec = make_int4(0x7fffffff, 0, 1, 0);
        if (l < 16 && sbeg + l < nseg) myrec = rec[base + sbeg + l];

        // ---- bf16 gather + mean + packed LDS A-stage (c==1 fast path) ----
        uint_t* Au = reinterpret_cast<uint_t*>(&Abuf[wv][0]);
        for (int s = 0; s < 16; ++s) {
            int row = __builtin_amdgcn_readfirstlane(__shfl(myrec.x, s));
            if (row < rowLo || row >= rowHi) continue;
            int eo = __builtin_amdgcn_readfirstlane(__shfl(myrec.y, s));
            int c  = __builtin_amdgcn_readfirstlane(__shfl(myrec.z, s));
            int src0 = ssrc2[eo];                       // uniform addr -> scalar broadcast
            const uint_t* rowU = reinterpret_cast<const uint_t*>(xbf + (size_t)src0 * 160);
            uint_t u0 = rowU[l];
            uint_t u1 = 0;
            if (l < 11) u1 = rowU[64 + l];
            if (c == 1) {
                // mean of one bf16 row == the row: direct copy, zero VALU math
                Au[s * 84 + uA] = u0;
                if (l < 11) Au[s * 84 + uB] = u1;
            } else {
                float a0 = bfLo(u0), a1 = bfHi(u0);
                float a2 = bfLo(u1), a3 = bfHi(u1);
                for (int k = 1; k < c; ++k) {
                    int src = ssrc2[eo + k];
                    const uint_t* rU = reinterpret_cast<const uint_t*>(
                        xbf + (size_t)src * 160);
                    uint_t v0 = rU[l];
                    a0 += bfLo(v0); a1 += bfHi(v0);
                    if (l < 11) {
                        uint_t v1 = rU[64 + l];
                        a2 += bfLo(v1); a3 += bfHi(v1);
                    }
                }
                float inv = 1.0f / (float)c;
                Au[s * 84 + uA] = (uint_t)f2bf(a0 * inv) | ((uint_t)f2bf(a1 * inv) << 16);
                if (l < 11)
                    Au[s * 84 + uB] = (uint_t)f2bf(a2 * inv) | ((uint_t)f2bf(a3 * inv) << 16);
            }
        }

        int rg[4]; bool rok[4];
        #pragma unroll
        for (int q = 0; q < 4; ++q) {
            rg[q] = __shfl(myrec.x, kg * 4 + q);
            rok[q] = (rg[q] >= rowLo) && (rg[q] < rowHi);
        }

        // ---- MFMA transform + fp16 store (invalid rows store-masked) ----
        #pragma unroll
        for (int b = 0; b < BNUM; ++b) {
            bf16x8 af = *reinterpret_cast<const bf16x8*>(
                &Abuf[wv][lr * ASTRIDE + b * 32 + kg * 8]);
            f32x4 z = {0.f, 0.f, 0.f, 0.f};
            f32x4 acc0 = __builtin_amdgcn_mfma_f32_16x16x32_bf16(af, bfr[b][0], z, 0, 0, 0);
            f32x4 acc1 = __builtin_amdgcn_mfma_f32_16x16x32_bf16(af, bfr[b][1], z, 0, 0, 0);
            #pragma unroll
            for (int q = 0; q < 4; ++q) {
                if (rok[q]) {
                    __half* orow = tseg + (size_t)(rg[q] - rowLo) * H + b * IB;
                    orow[lr] = __float2half(acc0[q]);
                    if (lr < 14) orow[16 + lr] = __float2half(acc1[q]);
                }
            }
        }
    }
}

// =============== per-dst aggregation (dst-major contiguous tseg) ===============

__global__ __launch_bounds__(256)
void k_aggadd(const __half* __restrict__ tseg, const int* __restrict__ dstbase,
              const float* __restrict__ rootsrc, float* __restrict__ fout,
              ushort_t* __restrict__ Abf, int relu, int s0, int s1) {
    int t = threadIdx.x, wv = t >> 6, l = t & 63;
    int segBase = dstbase[s0];
    for (int d = s0 + blockIdx.x * 4 + wv; d < s1; d += gridDim.x * 4) {
        int a = dstbase[d], bnd = dstbase[d + 1];
        const float* brow = rootsrc + (size_t)d * H;
        float2 acc0 = *reinterpret_cast<const float2*>(brow + 2 * l);
        float2 acc1 = make_float2(0.f, 0.f);
        if (l < 11) acc1 = *reinterpret_cast<const float2*>(brow + 128 + 2 * l);
        for (int s = a; s < bnd; ++s) {
            const __half2* trow = reinterpret_cast<const __half2*>(
                tseg + (size_t)(s - segBase) * H);
            float2 v = __half22float2(trow[l]);
            acc0.x += v.x; acc0.y += v.y;
            if (l < 11) {
                float2 v1 = __half22float2(trow[64 + l]);
                acc1.x += v1.x; acc1.y += v1.y;
            }
        }
        if (relu) {
            acc0.x = fmaxf(acc0.x, 0.f); acc0.y = fmaxf(acc0.y, 0.f);
            acc1.x = fmaxf(acc1.x, 0.f); acc1.y = fmaxf(acc1.y, 0.f);
        }
        if (fout) {
            float* frow = fout + (size_t)d * H;
            *reinterpret_cast<float2*>(frow + 2 * l) = acc0;
            if (l < 11) *reinterpret_cast<float2*>(frow + 128 + 2 * l) = acc1;
        }
        if (Abf) {
            ushort_t* arow = Abf + (size_t)d * 160;
            uint_t p0 = (uint_t)f2bf(acc0.x) | ((uint_t)f2bf(acc0.y) << 16);
            *reinterpret_cast<uint_t*>(arow + 2 * l) = p0;
            if (l < 11) {
                uint_t p1 = (uint_t)f2bf(acc1.x) | ((uint_t)f2bf(acc1.y) << 16);
                *reinterpret_cast<uint_t*>(arow + 128 + 2 * l) = p1;
            }
            if (l < 5) *reinterpret_cast<uint_t*>(arow + 150 + 2 * l) = 0;
        }
    }
}

extern "C" void kernel_launch(void* const* d_in, const int* in_sizes, int n_in,
                              void* d_out, int out_size, void* d_ws, size_t ws_size,
                              hipStream_t stream) {
    const float* node_emb = (const float*)d_in[0];
    const float* w1 = (const float*)d_in[1];
    const float* root1 = (const float*)d_in[2];
    const float* b1 = (const float*)d_in[3];
    const float* w2 = (const float*)d_in[4];
    const float* root2 = (const float*)d_in[5];
    const float* b2 = (const float*)d_in[6];
    const int* edge_index = (const int*)d_in[7];
    const int* edge_type = (const int*)d_in[8];
    int N_ = in_sizes[0] / H;
    int E_ = in_sizes[8];
    float* out = (float*)d_out;

    const int Ncells = N_ * RNUM;
    const int wbtot = RNUM * BNUM * 2 * 16 * 32;

    int* ws = (int*)d_ws;
    size_t off = 0;
    int* cnt      = ws + off; off += Ncells;
    size_t zero_units = off;                 // memset covers cnt only
    int* relbase2 = ws + off; off += 64;
    int* tprefix  = ws + off; off += 64;
    int* blkN     = ws + off; off += 64;
    int* blkD     = ws + off; off += 64;
    int* blkBN    = ws + off; off += 64;
    int* blkBD    = ws + off; off += 64;
    int* blkRelH  = ws + off; off += 64 * RNUM;
    int* blkRelB  = ws + off; off += 64 * RNUM;
    int* dstbase  = ws + off; off += N_ + 2;
    int* segoff   = ws + off; off += Ncells;
    int* ssrc2    = ws + off; off += E_;
    off = (off + 3) & ~(size_t)3;
    int4* rec     = (int4*)(ws + off); off += (size_t)4 * Ncells;
    ushort_t* wbf1 = (ushort_t*)(ws + off); off += wbtot / 2;
    ushort_t* wbf2 = (ushort_t*)(ws + off); off += wbtot / 2;
    ushort_t* Bbf1 = (ushort_t*)(ws + off); off += 12800;
    ushort_t* Bbf2 = (ushort_t*)(ws + off); off += 12800;
    ushort_t* xbf  = (ushort_t*)(ws + off); off += (size_t)N_ * 160 / 2;
    ushort_t* Abf  = (ushort_t*)(ws + off); off += (size_t)N_ * 160 / 2;
    float* rootbuf = (float*)(ws + off); off += (size_t)N_ * H;
    __half* tseg  = (__half*)(ws + off);
    size_t tsegOffB = off * 4;

    size_t availB = (ws_size > tsegOffB) ? (ws_size - tsegOffB) : 0;
    long long dps_ll = (long long)(availB / ((size_t)RNUM * H * 2));
    int dps = (dps_ll > N_) ? N_ : (int)dps_ll;
    if (dps < 1) dps = 1;
    int nstripe = (N_ + dps - 1) / dps;

    hipMemsetAsync(cnt, 0, zero_units * 4, stream);

    k_count<<<512, 256, 0, stream>>>(edge_index, edge_type, E_, cnt);
    int nscan = (N_ + SCAN_SPAN - 1) / SCAN_SPAN;   // <= 64 for N=20000
    k_scanA<<<nscan, SCAN_BLOCK, 0, stream>>>(cnt, N_, blkN, blkD, blkRelH);
    k_scanB<<<1, 64, 0, stream>>>(blkN, blkD, blkRelH, nscan, blkBN, blkBD,
                                  blkRelB, relbase2, tprefix);
    k_scanC<<<nscan, SCAN_BLOCK, 0, stream>>>(cnt, N_, blkBN, blkBD, blkRelB,
                                              dstbase, segoff, rec);
    k_scatter2<<<(E_ + 255) / 256, 256, 0, stream>>>(edge_index, edge_type, E_, segoff, ssrc2);
    long long preptot = 2LL * wbtot + 2 * 160 * 160 + (long long)N_ * 160;
    k_prep<<<(int)((preptot + 255) / 256), 256, 0, stream>>>(
        w1, w2, wbf1, wbf2, root1, root2, Bbf1, Bbf2, node_emb, xbf, N_);

    const int SEG_GRID = 1792;

    // ---- layer 1: gather from xbf (bf16) ----
    k_rootmm<<<dim3(40, 10), 256, 0, stream>>>(xbf, Bbf1, b1, rootbuf, N_);
    for (int st = 0; st < nstripe; ++st) {
        int s0 = st * dps;
        int s1 = s0 + dps; if (s1 > N_) s1 = N_;
        k_seg<<<SEG_GRID, 256, 0, stream>>>(rec, relbase2, tprefix, ssrc2, wbf1, xbf, tseg,
                                            dstbase + s0, dstbase + s1);
        k_aggadd<<<1280, 256, 0, stream>>>(tseg, dstbase, rootbuf, (float*)nullptr, Abf,
                                           1, s0, s1);
    }

    // ---- layer 2: gather from Abf (bf16) ----
    k_rootmm<<<dim3(40, 10), 256, 0, stream>>>(Abf, Bbf2, b2, out, N_);
    for (int st = 0; st < nstripe; ++st) {
        int s0 = st * dps;
        int s1 = s0 + dps; if (s1 > N_) s1 = N_;
        k_seg<<<SEG_GRID, 256, 0, stream>>>(rec, relbase2, tprefix, ssrc2, wbf2, Abf, tseg,
                                            dstbase + s0, dstbase + s1);
        k_aggadd<<<1280, 256, 0, stream>>>(tseg, dstbase, out, out, (ushort_t*)nullptr,
                                           0, s0, s1);
    }
}